// Round 7
// baseline (38.489 us; speedup 1.0000x reference)
//
#include <hip/hip_runtime.h>

#define NN 1024
#define EE 64

// K1a: partial[jc][i][e] = sum_{j in chunk} relu(cost[j][i]*w4[e] + b4[e])
// grid (16 i-tiles, nparts j-chunks), block 256.
// Wave layout: lane&15 -> i-float4 (64 i per wave), lane>>4 -> j-sub (4-way),
// wave id -> e-group (4 groups x 16 e). Each thread: acc[4i][16e] over jspan/4 j's.
// Loads: one float4 per (j, 4i) per e-group -> 1M float4 total (dup=4).
__global__ __launch_bounds__(256) void k1a_part(
    const float* __restrict__ cost,
    const float* __restrict__ w4, const float* __restrict__ b4,
    float* __restrict__ partial)
{
    const int it = blockIdx.x;            // 16 i-tiles of 64
    const int jc = blockIdx.y;            // nparts j-chunks
    const int jspan = NN / gridDim.y;
    const int tid = threadIdx.x;
    const int lane = tid & 63;
    const int eg = tid >> 6;              // 4 e-groups of 16
    const int i4 = lane & 15;
    const int js = lane >> 4;             // j-sub 0..3
    const int ibase = it * 64 + i4 * 4;

    float w4v[16], b4v[16];
#pragma unroll
    for (int e = 0; e < 16; ++e) {
        w4v[e] = w4[eg * 16 + e];
        b4v[e] = b4[eg * 16 + e];
    }

    float acc[4][16];
#pragma unroll
    for (int ii = 0; ii < 4; ++ii)
#pragma unroll
        for (int e = 0; e < 16; ++e) acc[ii][e] = 0.f;

    const float* cp = cost + (size_t)(jc * jspan + js) * NN + ibase;
    const int iters = jspan >> 2;
#pragma unroll 4
    for (int t = 0; t < iters; ++t) {
        float4 cv = *(const float4*)(cp + (size_t)4 * t * NN);
        float c0 = cv.x, c1 = cv.y, c2 = cv.z, c3 = cv.w;
#pragma unroll
        for (int e = 0; e < 16; ++e) {
            acc[0][e] += fmaxf(fmaf(c0, w4v[e], b4v[e]), 0.f);
            acc[1][e] += fmaxf(fmaf(c1, w4v[e], b4v[e]), 0.f);
            acc[2][e] += fmaxf(fmaf(c2, w4v[e], b4v[e]), 0.f);
            acc[3][e] += fmaxf(fmaf(c3, w4v[e], b4v[e]), 0.f);
        }
    }

    // combine the 4 j-subsets: lanes {l, l^16, l^32, l^48}
#pragma unroll
    for (int ii = 0; ii < 4; ++ii)
#pragma unroll
        for (int e = 0; e < 16; ++e) {
            float v = acc[ii][e];
            v += __shfl_xor(v, 16, 64);
            v += __shfl_xor(v, 32, 64);
            acc[ii][e] = v;
        }

    if (js == 0) {
#pragma unroll
        for (int ii = 0; ii < 4; ++ii) {
            float* dst = partial + ((size_t)jc * NN + ibase + ii) * EE + eg * 16;
#pragma unroll
            for (int ec = 0; ec < 4; ++ec)
                *(float4*)(dst + ec * 4) = make_float4(
                    acc[ii][ec * 4], acc[ii][ec * 4 + 1],
                    acc[ii][ec * 4 + 2], acc[ii][ec * 4 + 3]);
        }
    }
}

// K1b: base[i][e] = x[i]*W1[e] + b1[e] + sum_p partial[p][i][e]
// 256 blocks x 64 threads, one float4 of the flat (i,e) space per thread.
__global__ __launch_bounds__(64) void k1b_reduce(
    const float* __restrict__ nf,
    const float* __restrict__ W1, const float* __restrict__ b1,
    const float* __restrict__ partial, int nparts,
    float* __restrict__ base)
{
    const int flat = (blockIdx.x * 64 + threadIdx.x) * 4;  // 65536 elements
    const int i = flat >> 6;
    const int e0 = flat & 63;
    float4 s;
    float xi = nf[i];
    s.x = fmaf(xi, W1[e0],     b1[e0]);
    s.y = fmaf(xi, W1[e0 + 1], b1[e0 + 1]);
    s.z = fmaf(xi, W1[e0 + 2], b1[e0 + 2]);
    s.w = fmaf(xi, W1[e0 + 3], b1[e0 + 3]);
#pragma unroll 4
    for (int p = 0; p < nparts; ++p) {
        float4 v = *(const float4*)(partial + (size_t)p * (NN * EE) + flat);
        s.x += v.x; s.y += v.y; s.z += v.z; s.w += v.w;
    }
    *(float4*)(base + flat) = s;
}

// K23: fused scan + epilogue. 64 blocks x 1024 threads.
// Every block redundantly computes the 4-step scan (base is L2/L3-resident),
// then its 16 waves each produce one output row (16 rows/block).
__global__ __launch_bounds__(1024) void k23_fused(
    const float* __restrict__ base,
    const float* __restrict__ W2, const float* __restrict__ b2,
    const float* __restrict__ W5, const float* __restrict__ b5,
    const float* __restrict__ W6, const float* __restrict__ b6,
    const float* __restrict__ W7, const float* __restrict__ b7,
    float* __restrict__ q)
{
    __shared__ float W2L[64 * 65];
    __shared__ float W7L[64 * 65];
    __shared__ float sP[1024];
    __shared__ float sS[64];
    __shared__ float sV[64];
    __shared__ float embL[16 * 64];
    __shared__ float sC;

    const int tid = threadIdx.x;
    const int c = tid & 63;
    const int g = tid >> 6;

#pragma unroll
    for (int m = tid; m < 4096; m += 1024) {
        W2L[(m >> 6) * 65 + (m & 63)] = W2[m];
        W7L[(m >> 6) * 65 + (m & 63)] = W7[m];
    }

    float bl[64];
#pragma unroll
    for (int rr = 0; rr < 64; ++rr)
        bl[rr] = base[(size_t)(g * 64 + rr) * EE + c];

    if (tid < 64) sS[c] = 0.f;
    __syncthreads();

    for (int t = 0; t < 4; ++t) {
        if (tid < 64) {
            float v = b2[c];
#pragma unroll
            for (int k = 0; k < 64; ++k) v = fmaf(W2L[c * 65 + k], sS[k], v);
            sV[c] = v;
        }
        __syncthreads();
        float v2c = sV[c];
        float a0 = 0.f, a1 = 0.f, a2 = 0.f, a3 = 0.f;
#pragma unroll
        for (int rr = 0; rr < 64; rr += 4) {
            a0 += fmaxf(bl[rr]     + v2c, 0.f);
            a1 += fmaxf(bl[rr + 1] + v2c, 0.f);
            a2 += fmaxf(bl[rr + 2] + v2c, 0.f);
            a3 += fmaxf(bl[rr + 3] + v2c, 0.f);
        }
        sP[tid] = (a0 + a1) + (a2 + a3);
        __syncthreads();
        if (tid < 64) {
            float s = 0.f;
#pragma unroll
            for (int gg = 0; gg < 16; ++gg) s += sP[gg * 64 + c];
            sS[c] = s;
        }
        __syncthreads();
    }
    // sV holds v2_4; sS holds s_4.

    if (tid < 64) {
        float h = b6[c];
#pragma unroll
        for (int k = 0; k < 64; ++k) h = fmaf(W6[c * 64 + k], sS[k], h);
        float p = fmaxf(h, 0.f) * W5[c];
#pragma unroll
        for (int off = 32; off > 0; off >>= 1) p += __shfl_down(p, off, 64);
        if (tid == 0) sC = p;
    }

    const int i = blockIdx.x * 16 + g;
    embL[g * 64 + c] = fmaxf(base[(size_t)i * EE + c] + sV[c], 0.f);
    __syncthreads();

    float h = b7[c];
#pragma unroll
    for (int k = 0; k < 64; ++k)
        h = fmaf(embL[g * 64 + k], W7L[c * 65 + k], h);
    float p = fmaxf(h, 0.f) * W5[64 + c];
#pragma unroll
    for (int off = 32; off > 0; off >>= 1) p += __shfl_down(p, off, 64);
    if (c == 0) q[i] = p + sC + b5[0];
}

extern "C" void kernel_launch(void* const* d_in, const int* in_sizes, int n_in,
                              void* d_out, int out_size, void* d_ws, size_t ws_size,
                              hipStream_t stream)
{
    (void)in_sizes; (void)n_in; (void)out_size;
    const float* nf   = (const float*)d_in[0];
    const float* cost = (const float*)d_in[1];
    const float* W1   = (const float*)d_in[2];
    const float* b1   = (const float*)d_in[3];
    const float* W2   = (const float*)d_in[4];
    const float* b2   = (const float*)d_in[5];
    const float* w4   = (const float*)d_in[6];
    const float* b4   = (const float*)d_in[7];
    const float* W5   = (const float*)d_in[8];
    const float* b5   = (const float*)d_in[9];
    const float* W6   = (const float*)d_in[10];
    const float* b6   = (const float*)d_in[11];
    const float* W7   = (const float*)d_in[12];
    const float* b7   = (const float*)d_in[13];
    float* q = (float*)d_out;

    float* base = (float*)d_ws;              // NN*EE floats (16B aligned)
    float* part = base + (size_t)NN * EE;    // nparts * NN*EE floats

    size_t fixed = (size_t)NN * EE * sizeof(float);
    size_t per_part = (size_t)NN * EE * sizeof(float);
    int nparts = 32;
    while (nparts > 1 && fixed + (size_t)nparts * per_part > ws_size) nparts >>= 1;

    dim3 g1(16, nparts);
    k1a_part<<<g1, 256, 0, stream>>>(cost, w4, b4, part);
    k1b_reduce<<<256, 64, 0, stream>>>(nf, W1, b1, part, nparts, base);
    k23_fused<<<64, 1024, 0, stream>>>(base, W2, b2, W5, b5, W6, b6, W7, b7, q);
}

// Round 8
// 31.653 us; speedup vs baseline: 1.2160x; 1.2160x over previous
//
#include <hip/hip_runtime.h>

#define NN 1024
#define EE 64
#define NPARTS 16

// K1a: partial[jc][i][e] = sum_{j in chunk} relu(cost[j][i]*w4[e] + b4[e])
// EXACT R5 form (empirical best): grid (32 i-tiles, 16 j-chunks), block 256 =
// 32 i-lanes x 8 e-groups(8 e). dup-8 wave broadcast loads, unroll 8.
__global__ __launch_bounds__(256) void k1a_part(
    const float* __restrict__ cost,
    const float* __restrict__ w4, const float* __restrict__ b4,
    float* __restrict__ partial)
{
    const int it = blockIdx.x;
    const int jc = blockIdx.y;
    const int tid = threadIdx.x;
    const int il = tid & 31;
    const int eg = tid >> 5;
    const int i = it * 32 + il;
    const int j0 = jc * (NN / NPARTS);

    float w4v[8], b4v[8];
#pragma unroll
    for (int ee = 0; ee < 8; ++ee) {
        w4v[ee] = w4[eg * 8 + ee];
        b4v[ee] = b4[eg * 8 + ee];
    }
    float acc[8];
#pragma unroll
    for (int ee = 0; ee < 8; ++ee) acc[ee] = 0.f;

    const float* cp = cost + (size_t)j0 * NN + i;
#pragma unroll 8
    for (int jj = 0; jj < NN / NPARTS; ++jj) {
        float cv = cp[(size_t)jj * NN];
#pragma unroll
        for (int ee = 0; ee < 8; ++ee)
            acc[ee] += fmaxf(fmaf(cv, w4v[ee], b4v[ee]), 0.f);
    }
    float* dst = partial + ((size_t)jc * NN + i) * EE + eg * 8;
    *(float4*)(dst)     = make_float4(acc[0], acc[1], acc[2], acc[3]);
    *(float4*)(dst + 4) = make_float4(acc[4], acc[5], acc[6], acc[7]);
}

// K1b: base[i][e] = x[i]*W1[e] + b1[e] + sum_p partial[p][i][e]
// 64 blocks x 256 thr; one float4 of the flat (i,e) space per thread,
// 16 float4 reads (unroll 8 -> 8 in flight), 4 waves/block.
__global__ __launch_bounds__(256) void k1b_reduce(
    const float* __restrict__ nf,
    const float* __restrict__ W1, const float* __restrict__ b1,
    const float* __restrict__ partial,
    float* __restrict__ base)
{
    const int flat = (blockIdx.x * 256 + threadIdx.x) * 4;  // 65536 elements
    const int i = flat >> 6;
    const int e0 = flat & 63;
    float xi = nf[i];
    float4 s;
    s.x = fmaf(xi, W1[e0],     b1[e0]);
    s.y = fmaf(xi, W1[e0 + 1], b1[e0 + 1]);
    s.z = fmaf(xi, W1[e0 + 2], b1[e0 + 2]);
    s.w = fmaf(xi, W1[e0 + 3], b1[e0 + 3]);
#pragma unroll 8
    for (int p = 0; p < NPARTS; ++p) {
        float4 v = *(const float4*)(partial + (size_t)p * (NN * EE) + flat);
        s.x += v.x; s.y += v.y; s.z += v.z; s.w += v.w;
    }
    *(float4*)(base + flat) = s;
}

// K23: fused scan + epilogue. 64 blocks x 1024 threads.
// Every block redundantly computes the 4-step scan (base is L2/L3-resident),
// then its 16 waves each produce one output row (16 rows/block).
__global__ __launch_bounds__(1024) void k23_fused(
    const float* __restrict__ base,
    const float* __restrict__ W2, const float* __restrict__ b2,
    const float* __restrict__ W5, const float* __restrict__ b5,
    const float* __restrict__ W6, const float* __restrict__ b6,
    const float* __restrict__ W7, const float* __restrict__ b7,
    float* __restrict__ q)
{
    __shared__ float W2L[64 * 65];
    __shared__ float W7L[64 * 65];
    __shared__ float sP[1024];
    __shared__ float sS[64];
    __shared__ float sV[64];
    __shared__ float embL[16 * 64];
    __shared__ float sC;

    const int tid = threadIdx.x;
    const int c = tid & 63;
    const int g = tid >> 6;

#pragma unroll
    for (int m = tid; m < 4096; m += 1024) {
        W2L[(m >> 6) * 65 + (m & 63)] = W2[m];
        W7L[(m >> 6) * 65 + (m & 63)] = W7[m];
    }

    float bl[64];
#pragma unroll
    for (int rr = 0; rr < 64; ++rr)
        bl[rr] = base[(size_t)(g * 64 + rr) * EE + c];

    if (tid < 64) sS[c] = 0.f;
    __syncthreads();

    for (int t = 0; t < 4; ++t) {
        if (tid < 64) {
            float v = b2[c];
#pragma unroll
            for (int k = 0; k < 64; ++k) v = fmaf(W2L[c * 65 + k], sS[k], v);
            sV[c] = v;
        }
        __syncthreads();
        float v2c = sV[c];
        float a0 = 0.f, a1 = 0.f, a2 = 0.f, a3 = 0.f;
#pragma unroll
        for (int rr = 0; rr < 64; rr += 4) {
            a0 += fmaxf(bl[rr]     + v2c, 0.f);
            a1 += fmaxf(bl[rr + 1] + v2c, 0.f);
            a2 += fmaxf(bl[rr + 2] + v2c, 0.f);
            a3 += fmaxf(bl[rr + 3] + v2c, 0.f);
        }
        sP[tid] = (a0 + a1) + (a2 + a3);
        __syncthreads();
        if (tid < 64) {
            float s = 0.f;
#pragma unroll
            for (int gg = 0; gg < 16; ++gg) s += sP[gg * 64 + c];
            sS[c] = s;
        }
        __syncthreads();
    }
    // sV holds v2_4; sS holds s_4.

    if (tid < 64) {
        float h = b6[c];
#pragma unroll
        for (int k = 0; k < 64; ++k) h = fmaf(W6[c * 64 + k], sS[k], h);
        float p = fmaxf(h, 0.f) * W5[c];
#pragma unroll
        for (int off = 32; off > 0; off >>= 1) p += __shfl_down(p, off, 64);
        if (tid == 0) sC = p;
    }

    const int i = blockIdx.x * 16 + g;
    embL[g * 64 + c] = fmaxf(base[(size_t)i * EE + c] + sV[c], 0.f);
    __syncthreads();

    float h = b7[c];
#pragma unroll
    for (int k = 0; k < 64; ++k)
        h = fmaf(embL[g * 64 + k], W7L[c * 65 + k], h);
    float p = fmaxf(h, 0.f) * W5[64 + c];
#pragma unroll
    for (int off = 32; off > 0; off >>= 1) p += __shfl_down(p, off, 64);
    if (c == 0) q[i] = p + sC + b5[0];
}

extern "C" void kernel_launch(void* const* d_in, const int* in_sizes, int n_in,
                              void* d_out, int out_size, void* d_ws, size_t ws_size,
                              hipStream_t stream)
{
    (void)in_sizes; (void)n_in; (void)out_size; (void)ws_size;
    const float* nf   = (const float*)d_in[0];
    const float* cost = (const float*)d_in[1];
    const float* W1   = (const float*)d_in[2];
    const float* b1   = (const float*)d_in[3];
    const float* W2   = (const float*)d_in[4];
    const float* b2   = (const float*)d_in[5];
    const float* w4   = (const float*)d_in[6];
    const float* b4   = (const float*)d_in[7];
    const float* W5   = (const float*)d_in[8];
    const float* b5   = (const float*)d_in[9];
    const float* W6   = (const float*)d_in[10];
    const float* b6   = (const float*)d_in[11];
    const float* W7   = (const float*)d_in[12];
    const float* b7   = (const float*)d_in[13];
    float* q = (float*)d_out;

    float* base = (float*)d_ws;              // NN*EE floats (16B aligned)
    float* part = base + (size_t)NN * EE;    // NPARTS * NN*EE floats

    dim3 g1(32, NPARTS);
    k1a_part<<<g1, 256, 0, stream>>>(cost, w4, b4, part);
    k1b_reduce<<<64, 256, 0, stream>>>(nf, W1, b1, part, base);
    k23_fused<<<64, 1024, 0, stream>>>(base, W2, b2, W5, b5, W6, b6, W7, b7, q);
}